// Round 5
// baseline (1936.152 us; speedup 1.0000x reference)
//
#include <hip/hip_runtime.h>
#include <cmath>

// Persistent weight-stationary LSTM decode. B=64, H=2048, steps=30.
// gates_t = W_sum @ h_t (t>=1, since x_t == h_t), W_hh @ h_0 at t=0.
// One block per CU (grid=256); each block holds its 32 gate-rows (8 hidden
// units x 4 gates) of the weight matrix as fp16 MFMA A-fragments in LDS
// (131 KB), c in LDS fp32, and iterates all steps with a flag-array grid
// barrier (per-block release STORES, not RMW -- a single shared counter
// serialized 256 cross-XCD RMWs at ~50 us/barrier in R4).

#define HID   2048
#define BATCH 64
#define G4    8192
#define NCU   256                 // persistent grid size == CU count
#define HGRP  (HID * BATCH / 8)   // half8 groups per h slot

typedef __attribute__((ext_vector_type(8))) _Float16 half8;
typedef __attribute__((ext_vector_type(4))) float f32x4;

// LDS layout (bytes):
//   [0,      131072)  Wlds  : half8 frags [(mt*64+kt)*64+lane]
//   [131072, 139264)  gates : f32 [32 rows][64 batch]
//   [139264, 155648)  red   : f32x4 [(slot*4+nt)*64+lane]  (4 slots)
//   [155648, 157696)  cbuf  : f32 [8 units][64 batch]
//   [157696, 159744)  ybuf  : f32 [8 units][64 batch]
#define LDS_BYTES 159744

// ---- init: pack token -> h slot 0 (B-fragment layout), bsum, barrier flags ----
__global__ void k_init(const float* __restrict__ token, const float* __restrict__ bih,
                       const float* __restrict__ bhh, half8* __restrict__ h0p,
                       float* __restrict__ bsum, unsigned* __restrict__ flags) {
    int g = blockIdx.x * 256 + threadIdx.x;          // [0, 16384)
    int l = g & 63, nt = (g >> 6) & 3, kt = g >> 8;
    int n = nt * 16 + (l & 15);
    int k0 = kt * 32 + (l >> 4) * 8;
    const float4* ps = (const float4*)(token + (size_t)n * HID + k0);
    float4 a = ps[0], b = ps[1];
    half8 v;
    v[0]=(_Float16)a.x; v[1]=(_Float16)a.y; v[2]=(_Float16)a.z; v[3]=(_Float16)a.w;
    v[4]=(_Float16)b.x; v[5]=(_Float16)b.y; v[6]=(_Float16)b.z; v[7]=(_Float16)b.w;
    h0p[g] = v;
    if (g < G4) bsum[g] = bih[g] + bhh[g];
    if (g < NCU) flags[g] = 0u;
}

// ---- the persistent kernel ----
__global__ __launch_bounds__(512, 2)
void k_lstm(const float* __restrict__ wih, const float* __restrict__ whh,
            const float* __restrict__ bsum, const float* __restrict__ wout,
            _Float16* __restrict__ hbuf,     // 2 ping-pong slots, fragment layout
            float* __restrict__ ypart,       // [steps][NCU][64]
            unsigned* __restrict__ flags, int steps) {
    extern __shared__ char smem[];
    half8* Wlds  = (half8*)smem;
    float* gates = (float*)(smem + 131072);
    f32x4* red4  = (f32x4*)(smem + 139264);
    float* cbuf  = (float*)(smem + 155648);
    float* ybuf  = (float*)(smem + 157696);

    const int tid  = threadIdx.x;
    const int blk  = blockIdx.x;
    const int lane = tid & 63;
    const int w    = tid >> 6;        // wave 0..7
    const int mt   = w & 1;           // m-tile (tile0 = i,f rows; tile1 = g,o rows)
    const int ks   = w >> 1;          // k-split slice 0..3 (512 k each)

    // prologue: stage W_hh rows for this block's 32 gate-rows as fp16 A-frags
    for (int idx = tid; idx < 2 * 64 * 64; idx += 512) {
        int l = idx & 63, kt = (idx >> 6) & 63, m2 = idx >> 12;
        int m = l & 15;
        int gate = m2 * 2 + (m >> 3);
        int row  = gate * HID + blk * 8 + (m & 7);
        int col  = kt * 32 + (l >> 4) * 8;
        const float4* p = (const float4*)(whh + (size_t)row * HID + col);
        float4 a = p[0], b = p[1];
        half8 v;
        v[0]=(_Float16)a.x; v[1]=(_Float16)a.y; v[2]=(_Float16)a.z; v[3]=(_Float16)a.w;
        v[4]=(_Float16)b.x; v[5]=(_Float16)b.y; v[6]=(_Float16)b.z; v[7]=(_Float16)b.w;
        Wlds[idx] = v;
    }
    cbuf[tid] = 0.0f;                 // 512 floats, one per thread

    // bias for the gates-writeback waves (ks==0): 4 rows per lane
    float bias_r[4];
    if (ks == 0) {
        const int q = lane >> 4;
        #pragma unroll
        for (int r = 0; r < 4; ++r) {
            int m = q * 4 + r;
            bias_r[r] = bsum[(mt * 2 + (m >> 3)) * HID + blk * 8 + (m & 7)];
        }
    }
    const float wj = wout[blk * 8 + w];   // this wave's output weight (unit j)
    __syncthreads();

    for (int t = 0; t < steps; ++t) {
        const half8* hp = (const half8*)(hbuf + (size_t)(t & 1) * HID * BATCH);
        f32x4 a0 = {0,0,0,0}, a1 = {0,0,0,0}, a2 = {0,0,0,0}, a3 = {0,0,0,0};
        const int ktb = ks * 16;
        #pragma unroll 8
        for (int kk = 0; kk < 16; ++kk) {
            int kt = ktb + kk;
            half8 av = Wlds[(mt * 64 + kt) * 64 + lane];
            half8 b0 = hp[(kt * 4 + 0) * 64 + lane];
            half8 b1 = hp[(kt * 4 + 1) * 64 + lane];
            half8 b2 = hp[(kt * 4 + 2) * 64 + lane];
            half8 b3 = hp[(kt * 4 + 3) * 64 + lane];
            a0 = __builtin_amdgcn_mfma_f32_16x16x32_f16(av, b0, a0, 0, 0, 0);
            a1 = __builtin_amdgcn_mfma_f32_16x16x32_f16(av, b1, a1, 0, 0, 0);
            a2 = __builtin_amdgcn_mfma_f32_16x16x32_f16(av, b2, a2, 0, 0, 0);
            a3 = __builtin_amdgcn_mfma_f32_16x16x32_f16(av, b3, a3, 0, 0, 0);
        }
        // k-split reduction: 4 -> 2 -> 1 via LDS (layout (slot*4+nt)*64+lane: conflict-free)
        if (ks == 1 || ks == 3) {
            int slot = mt + (ks == 3 ? 2 : 0);
            red4[(slot * 4 + 0) * 64 + lane] = a0;
            red4[(slot * 4 + 1) * 64 + lane] = a1;
            red4[(slot * 4 + 2) * 64 + lane] = a2;
            red4[(slot * 4 + 3) * 64 + lane] = a3;
        }
        __syncthreads();
        if (ks == 0 || ks == 2) {
            int slot = mt + (ks == 2 ? 2 : 0);
            a0 += red4[(slot * 4 + 0) * 64 + lane];
            a1 += red4[(slot * 4 + 1) * 64 + lane];
            a2 += red4[(slot * 4 + 2) * 64 + lane];
            a3 += red4[(slot * 4 + 3) * 64 + lane];
        }
        __syncthreads();
        if (ks == 2) {
            red4[(mt * 4 + 0) * 64 + lane] = a0;
            red4[(mt * 4 + 1) * 64 + lane] = a1;
            red4[(mt * 4 + 2) * 64 + lane] = a2;
            red4[(mt * 4 + 3) * 64 + lane] = a3;
        }
        __syncthreads();
        if (ks == 0) {
            a0 += red4[(mt * 4 + 0) * 64 + lane];
            a1 += red4[(mt * 4 + 1) * 64 + lane];
            a2 += red4[(mt * 4 + 2) * 64 + lane];
            a3 += red4[(mt * 4 + 3) * 64 + lane];
            const int q = lane >> 4, col = lane & 15;
            #pragma unroll
            for (int r = 0; r < 4; ++r) {
                float* gr = gates + (mt * 16 + q * 4 + r) * 64 + col;
                gr[0]  = a0[r] + bias_r[r];
                gr[16] = a1[r] + bias_r[r];
                gr[32] = a2[r] + bias_r[r];
                gr[48] = a3[r] + bias_r[r];
            }
        }
        __syncthreads();
        // pointwise: wave w = local unit j, lane = batch b
        {
            const int b = lane;
            float gi = gates[(0  + w) * 64 + b];
            float gf = gates[(8  + w) * 64 + b];
            float gg = gates[(16 + w) * 64 + b];
            float go = gates[(24 + w) * 64 + b];
            float iv = 1.0f / (1.0f + __expf(-gi));
            float fv = 1.0f / (1.0f + __expf(-gf));
            float gv = tanhf(gg);
            float ov = 1.0f / (1.0f + __expf(-go));
            float cn = fv * cbuf[w * 64 + b] + iv * gv;
            cbuf[w * 64 + b] = cn;
            float hv = ov * tanhf(cn);
            // scatter h into next slot's B-fragment layout (k = global unit idx)
            int k = blk * 8 + w;
            int kt = k >> 5, quad = (k & 31) >> 3, e = k & 7;
            int nt = b >> 4, lp = quad * 16 + (b & 15);
            _Float16* hn = hbuf + (size_t)((t + 1) & 1) * HID * BATCH;
            hn[((size_t)(kt * 4 + nt) * 64 + lp) * 8 + e] = (_Float16)hv;
            ybuf[w * 64 + b] = hv * wj;
        }
        __syncthreads();
        if (tid < 64) {
            float s = ybuf[tid];
            #pragma unroll
            for (int u = 1; u < 8; ++u) s += ybuf[u * 64 + tid];
            ypart[((size_t)t * NCU + blk) * 64 + tid] = s;
        }
        if (t == 0) {
            // upgrade Wlds in place: W_hh -> W_sum (+= W_ih). All step-0 MFMA
            // reads of Wlds completed before the reduction syncthreads above.
            for (int idx = tid; idx < 2 * 64 * 64; idx += 512) {
                int l = idx & 63, kt = (idx >> 6) & 63, m2 = idx >> 12;
                int m = l & 15;
                int gate = m2 * 2 + (m >> 3);
                int row  = gate * HID + blk * 8 + (m & 7);
                int col  = kt * 32 + (l >> 4) * 8;
                const float4* p = (const float4*)(wih + (size_t)row * HID + col);
                float4 a = p[0], b = p[1];
                half8 v = Wlds[idx];
                v[0] = (_Float16)((float)v[0] + a.x); v[1] = (_Float16)((float)v[1] + a.y);
                v[2] = (_Float16)((float)v[2] + a.z); v[3] = (_Float16)((float)v[3] + a.w);
                v[4] = (_Float16)((float)v[4] + b.x); v[5] = (_Float16)((float)v[5] + b.y);
                v[6] = (_Float16)((float)v[6] + b.z); v[7] = (_Float16)((float)v[7] + b.w);
                Wlds[idx] = v;
            }
        }
        if (t < steps - 1) {
            // flag-array grid barrier: 256 co-resident blocks (1/CU by LDS size).
            // Arrival is a plain agent-scope STORE per block (no RMW ownership
            // serialization); waiters spin on their own flag -- lanes 0..63 of
            // each of waves 0..3 cover the 256 flags with coalesced loads.
            __syncthreads();                       // all h stores ack'd (vmcnt 0)
            if (tid == 0) {
                __threadfence();                   // release: write back dirty L2
                __hip_atomic_store(&flags[blk], (unsigned)(t + 1),
                                   __ATOMIC_RELEASE, __HIP_MEMORY_SCOPE_AGENT);
            }
            if (tid < NCU) {
                while (__hip_atomic_load(&flags[tid], __ATOMIC_ACQUIRE,
                                         __HIP_MEMORY_SCOPE_AGENT) <= (unsigned)t)
                    __builtin_amdgcn_s_sleep(1);
            }
            __syncthreads();
            __threadfence();                       // acquire: drop stale L1/L2 lines
        }
    }
}

// ---- final: out[b][t] = bout + sum over 256 CU partials ----
__global__ void k_yout(const float* __restrict__ ypart, const float* __restrict__ bout,
                       float* __restrict__ out, int steps) {
    int t = blockIdx.x;
    int b = threadIdx.x;                           // 64 threads
    const float* p = ypart + (size_t)t * NCU * 64 + b;
    float s = bout[0];
    #pragma unroll 8
    for (int cu = 0; cu < NCU; ++cu) s += p[(size_t)cu * 64];
    out[(size_t)b * steps + t] = s;
}

extern "C" void kernel_launch(void* const* d_in, const int* in_sizes, int n_in,
                              void* d_out, int out_size, void* d_ws, size_t ws_size,
                              hipStream_t stream) {
    const float* token = (const float*)d_in[0];
    const float* wih   = (const float*)d_in[2];
    const float* whh   = (const float*)d_in[3];
    const float* bih   = (const float*)d_in[4];
    const float* bhh   = (const float*)d_in[5];
    const float* wout  = (const float*)d_in[6];
    const float* bout  = (const float*)d_in[7];
    float* out = (float*)d_out;
    const int steps = out_size / BATCH;            // 30

    char* ws = (char*)d_ws;
    size_t off = 0;
    auto carve = [&](size_t bytes) -> void* {
        void* p = ws + off;
        off = (off + bytes + 255) & ~(size_t)255;
        return p;
    };
    _Float16* hbuf  = (_Float16*)carve((size_t)2 * HID * BATCH * 2);   // 512 KB
    float*    bsum  = (float*)carve((size_t)G4 * 4);                   // 32 KB
    float*    ypart = (float*)carve((size_t)steps * NCU * 64 * 4);     // ~2 MB
    unsigned* flags = (unsigned*)carve(NCU * 4);

    hipFuncSetAttribute(reinterpret_cast<const void*>(&k_lstm),
                        hipFuncAttributeMaxDynamicSharedMemorySize, LDS_BYTES);

    k_init<<<dim3(HGRP / 256), dim3(256), 0, stream>>>(
        token, bih, bhh, (half8*)hbuf, bsum, flags);

    k_lstm<<<dim3(NCU), dim3(512), LDS_BYTES, stream>>>(
        wih, whh, bsum, wout, hbuf, ypart, flags, steps);

    k_yout<<<dim3(steps), dim3(64), 0, stream>>>(ypart, bout, out, steps);
}

// Round 6
// 707.372 us; speedup vs baseline: 2.7371x; 2.7371x over previous
//
#include <hip/hip_runtime.h>
#include <cmath>

// Persistent weight-stationary LSTM decode. B=64, H=2048, steps=30.
// gates_t = W_sum @ h_t (t>=1, since x_t == h_t), W_hh @ h_0 at t=0.
// One block per CU (grid=256); each block holds its 32 gate-rows of the weight
// matrix as fp16 MFMA A-fragments in LDS (131 KB), c in LDS fp32.
// Grid barrier v3: cache-maintenance ops (buffer_wbl2/inv inside
// __threadfence) are CACHE-WIDE, so execute them in ONE thread per block
// bracketed by __syncthreads; spin on per-block flags with RELAXED agent
// loads (acquire-per-poll in R5 caused a device-wide invalidate storm,
// ~50 us/barrier). Wave roles (nt-pair, ks) dedup the h-fragment loads
// (256 KB/block/step instead of 512).

#define HID   2048
#define BATCH 64
#define G4    8192
#define NCU   256                 // persistent grid size == CU count
#define HGRP  (HID * BATCH / 8)   // half8 groups per h slot

typedef __attribute__((ext_vector_type(8))) _Float16 half8;
typedef __attribute__((ext_vector_type(4))) float f32x4;

// LDS layout (bytes):
//   [0,      131072)  Wlds  : half8 frags [(mt*64+kt)*64+lane]
//   [131072, 139264)  gates : f32 [32 rows][64 batch]
//   [139264, 155648)  red   : f32x4 [(srow*4+p)*64+lane]  (4 srows)
//   [155648, 157696)  cbuf  : f32 [8 units][64 batch]
//   [157696, 159744)  ybuf  : f32 [8 units][64 batch]
#define LDS_BYTES 159744

// ---- init: pack token -> h slot 0 (B-fragment layout), bsum, barrier flags ----
__global__ void k_init(const float* __restrict__ token, const float* __restrict__ bih,
                       const float* __restrict__ bhh, half8* __restrict__ h0p,
                       float* __restrict__ bsum, unsigned* __restrict__ flags) {
    int g = blockIdx.x * 256 + threadIdx.x;          // [0, 16384)
    int l = g & 63, nt = (g >> 6) & 3, kt = g >> 8;
    int n = nt * 16 + (l & 15);
    int k0 = kt * 32 + (l >> 4) * 8;
    const float4* ps = (const float4*)(token + (size_t)n * HID + k0);
    float4 a = ps[0], b = ps[1];
    half8 v;
    v[0]=(_Float16)a.x; v[1]=(_Float16)a.y; v[2]=(_Float16)a.z; v[3]=(_Float16)a.w;
    v[4]=(_Float16)b.x; v[5]=(_Float16)b.y; v[6]=(_Float16)b.z; v[7]=(_Float16)b.w;
    h0p[g] = v;
    if (g < G4) bsum[g] = bih[g] + bhh[g];
    if (g < NCU) flags[g] = 0u;
}

// ---- the persistent kernel ----
__global__ __launch_bounds__(512, 2)
void k_lstm(const float* __restrict__ wih, const float* __restrict__ whh,
            const float* __restrict__ bsum, const float* __restrict__ wout,
            _Float16* __restrict__ hbuf,     // 2 ping-pong slots, fragment layout
            float* __restrict__ ypart,       // [steps][NCU][64]
            unsigned* __restrict__ flags, int steps) {
    extern __shared__ char smem[];
    half8* Wlds  = (half8*)smem;
    float* gates = (float*)(smem + 131072);
    f32x4* red4  = (f32x4*)(smem + 139264);
    float* cbuf  = (float*)(smem + 155648);
    float* ybuf  = (float*)(smem + 157696);

    const int tid  = threadIdx.x;
    const int blk  = blockIdx.x;
    const int lane = tid & 63;
    const int w    = tid >> 6;        // wave 0..7
    const int half = w & 1;           // n-tile pair: nt in {2*half, 2*half+1}
    const int ks   = w >> 1;          // k-split slice 0..3 (512 k each)

    // prologue: stage W_hh rows for this block's 32 gate-rows as fp16 A-frags
    for (int idx = tid; idx < 2 * 64 * 64; idx += 512) {
        int l = idx & 63, kt = (idx >> 6) & 63, m2 = idx >> 12;
        int m = l & 15;
        int gate = m2 * 2 + (m >> 3);
        int row  = gate * HID + blk * 8 + (m & 7);
        int col  = kt * 32 + (l >> 4) * 8;
        const float4* p = (const float4*)(whh + (size_t)row * HID + col);
        float4 a = p[0], b = p[1];
        half8 v;
        v[0]=(_Float16)a.x; v[1]=(_Float16)a.y; v[2]=(_Float16)a.z; v[3]=(_Float16)a.w;
        v[4]=(_Float16)b.x; v[5]=(_Float16)b.y; v[6]=(_Float16)b.z; v[7]=(_Float16)b.w;
        Wlds[idx] = v;
    }
    cbuf[tid] = 0.0f;                 // 512 floats, one per thread

    // bias for the gates-writeback waves (ks==0), both m-tiles
    float bias_r[2][4];
    if (ks == 0) {
        const int q = lane >> 4;
        #pragma unroll
        for (int mt2 = 0; mt2 < 2; ++mt2)
            #pragma unroll
            for (int r = 0; r < 4; ++r) {
                int m16 = q * 4 + r;
                bias_r[mt2][r] = bsum[(mt2 * 2 + (m16 >> 3)) * HID + blk * 8 + (m16 & 7)];
            }
    }
    const float wj = wout[blk * 8 + w];   // this wave's output weight (unit j)
    __syncthreads();

    for (int t = 0; t < steps; ++t) {
        const half8* hp = (const half8*)(hbuf + (size_t)(t & 1) * HID * BATCH);
        // acc[p]: p = mt*2 + j, covering (mt, nt=2*half+j)
        f32x4 a00 = {0,0,0,0}, a01 = {0,0,0,0}, a10 = {0,0,0,0}, a11 = {0,0,0,0};
        const int ktb = ks * 16;
        #pragma unroll 8
        for (int kk = 0; kk < 16; ++kk) {
            int kt = ktb + kk;
            half8 av0 = Wlds[(kt) * 64 + lane];            // mt=0
            half8 av1 = Wlds[(64 + kt) * 64 + lane];       // mt=1
            half8 b0  = hp[(kt * 4 + half * 2 + 0) * 64 + lane];
            half8 b1  = hp[(kt * 4 + half * 2 + 1) * 64 + lane];
            a00 = __builtin_amdgcn_mfma_f32_16x16x32_f16(av0, b0, a00, 0, 0, 0);
            a01 = __builtin_amdgcn_mfma_f32_16x16x32_f16(av0, b1, a01, 0, 0, 0);
            a10 = __builtin_amdgcn_mfma_f32_16x16x32_f16(av1, b0, a10, 0, 0, 0);
            a11 = __builtin_amdgcn_mfma_f32_16x16x32_f16(av1, b1, a11, 0, 0, 0);
        }
        // k-split reduction 4 -> 2 -> 1 via LDS
        if (ks == 1 || ks == 3) {
            int srow = (ks == 3 ? 2 : 0) + half;
            red4[(srow * 4 + 0) * 64 + lane] = a00;
            red4[(srow * 4 + 1) * 64 + lane] = a01;
            red4[(srow * 4 + 2) * 64 + lane] = a10;
            red4[(srow * 4 + 3) * 64 + lane] = a11;
        }
        __syncthreads();
        if (ks == 0 || ks == 2) {
            int srow = (ks == 2 ? 2 : 0) + half;
            a00 += red4[(srow * 4 + 0) * 64 + lane];
            a01 += red4[(srow * 4 + 1) * 64 + lane];
            a10 += red4[(srow * 4 + 2) * 64 + lane];
            a11 += red4[(srow * 4 + 3) * 64 + lane];
        }
        __syncthreads();
        if (ks == 2) {
            red4[(half * 4 + 0) * 64 + lane] = a00;
            red4[(half * 4 + 1) * 64 + lane] = a01;
            red4[(half * 4 + 2) * 64 + lane] = a10;
            red4[(half * 4 + 3) * 64 + lane] = a11;
        }
        __syncthreads();
        if (ks == 0) {
            a00 += red4[(half * 4 + 0) * 64 + lane];
            a01 += red4[(half * 4 + 1) * 64 + lane];
            a10 += red4[(half * 4 + 2) * 64 + lane];
            a11 += red4[(half * 4 + 3) * 64 + lane];
            const int q = lane >> 4, col = lane & 15;
            #pragma unroll
            for (int r = 0; r < 4; ++r) {
                float* g0 = gates + (q * 4 + r) * 64 + (half * 2) * 16 + col;       // mt=0
                float* g1 = gates + (16 + q * 4 + r) * 64 + (half * 2) * 16 + col;  // mt=1
                g0[0]  = a00[r] + bias_r[0][r];
                g0[16] = a01[r] + bias_r[0][r];
                g1[0]  = a10[r] + bias_r[1][r];
                g1[16] = a11[r] + bias_r[1][r];
            }
        }
        __syncthreads();
        // pointwise: wave w = local unit j, lane = batch b
        {
            const int b = lane;
            float gi = gates[(0  + w) * 64 + b];
            float gf = gates[(8  + w) * 64 + b];
            float gg = gates[(16 + w) * 64 + b];
            float go = gates[(24 + w) * 64 + b];
            float iv = 1.0f / (1.0f + __expf(-gi));
            float fv = 1.0f / (1.0f + __expf(-gf));
            float gv = tanhf(gg);
            float ov = 1.0f / (1.0f + __expf(-go));
            float cn = fv * cbuf[w * 64 + b] + iv * gv;
            cbuf[w * 64 + b] = cn;
            float hv = ov * tanhf(cn);
            // scatter h into next slot's B-fragment layout (k = global unit idx)
            int k = blk * 8 + w;
            int kt = k >> 5, quad = (k & 31) >> 3, e = k & 7;
            int nt = b >> 4, lp = quad * 16 + (b & 15);
            _Float16* hn = hbuf + (size_t)((t + 1) & 1) * HID * BATCH;
            hn[((size_t)(kt * 4 + nt) * 64 + lp) * 8 + e] = (_Float16)hv;
            ybuf[w * 64 + b] = hv * wj;
        }
        __syncthreads();
        if (tid < 64) {
            float s = ybuf[tid];
            #pragma unroll
            for (int u = 1; u < 8; ++u) s += ybuf[u * 64 + tid];
            ypart[((size_t)t * NCU + blk) * 64 + tid] = s;
        }
        if (t == 0) {
            // upgrade Wlds in place: W_hh -> W_sum (+= W_ih). All step-0 MFMA
            // reads of Wlds are long done (multiple barriers above).
            for (int idx = tid; idx < 2 * 64 * 64; idx += 512) {
                int l = idx & 63, kt = (idx >> 6) & 63, m2 = idx >> 12;
                int m = l & 15;
                int gate = m2 * 2 + (m >> 3);
                int row  = gate * HID + blk * 8 + (m & 7);
                int col  = kt * 32 + (l >> 4) * 8;
                const float4* p = (const float4*)(wih + (size_t)row * HID + col);
                float4 a = p[0], b = p[1];
                half8 v = Wlds[idx];
                v[0] = (_Float16)((float)v[0] + a.x); v[1] = (_Float16)((float)v[1] + a.y);
                v[2] = (_Float16)((float)v[2] + a.z); v[3] = (_Float16)((float)v[3] + a.w);
                v[4] = (_Float16)((float)v[4] + b.x); v[5] = (_Float16)((float)v[5] + b.y);
                v[6] = (_Float16)((float)v[6] + b.z); v[7] = (_Float16)((float)v[7] + b.w);
                Wlds[idx] = v;
            }
        }
        if (t < steps - 1) {
            // grid barrier v3 (see header).
            __syncthreads();                       // all waves' stores vmcnt-drained
            if (tid == 0) {
                __threadfence();                   // ONE cache-wide writeback (release)
                __hip_atomic_store(&flags[blk], (unsigned)(t + 1),
                                   __ATOMIC_RELAXED, __HIP_MEMORY_SCOPE_AGENT);
            }
            if (tid < NCU) {
                while (__hip_atomic_load(&flags[tid], __ATOMIC_RELAXED,
                                         __HIP_MEMORY_SCOPE_AGENT) <= (unsigned)t)
                    __builtin_amdgcn_s_sleep(2);
            }
            __syncthreads();                       // all 256 flags observed
            if (tid == 0) __threadfence();         // ONE cache-wide invalidate (acquire)
            __syncthreads();                       // inv complete before h reads
        }
    }
}

// ---- final: out[b][t] = bout + sum over 256 CU partials ----
__global__ void k_yout(const float* __restrict__ ypart, const float* __restrict__ bout,
                       float* __restrict__ out, int steps) {
    int t = blockIdx.x;
    int b = threadIdx.x;                           // 64 threads
    const float* p = ypart + (size_t)t * NCU * 64 + b;
    float s = bout[0];
    #pragma unroll 8
    for (int cu = 0; cu < NCU; ++cu) s += p[(size_t)cu * 64];
    out[(size_t)b * steps + t] = s;
}

extern "C" void kernel_launch(void* const* d_in, const int* in_sizes, int n_in,
                              void* d_out, int out_size, void* d_ws, size_t ws_size,
                              hipStream_t stream) {
    const float* token = (const float*)d_in[0];
    const float* wih   = (const float*)d_in[2];
    const float* whh   = (const float*)d_in[3];
    const float* bih   = (const float*)d_in[4];
    const float* bhh   = (const float*)d_in[5];
    const float* wout  = (const float*)d_in[6];
    const float* bout  = (const float*)d_in[7];
    float* out = (float*)d_out;
    const int steps = out_size / BATCH;            // 30

    char* ws = (char*)d_ws;
    size_t off = 0;
    auto carve = [&](size_t bytes) -> void* {
        void* p = ws + off;
        off = (off + bytes + 255) & ~(size_t)255;
        return p;
    };
    _Float16* hbuf  = (_Float16*)carve((size_t)2 * HID * BATCH * 2);   // 512 KB
    float*    bsum  = (float*)carve((size_t)G4 * 4);                   // 32 KB
    float*    ypart = (float*)carve((size_t)steps * NCU * 64 * 4);     // ~2 MB
    unsigned* flags = (unsigned*)carve(NCU * 4);

    hipFuncSetAttribute(reinterpret_cast<const void*>(&k_lstm),
                        hipFuncAttributeMaxDynamicSharedMemorySize, LDS_BYTES);

    k_init<<<dim3(HGRP / 256), dim3(256), 0, stream>>>(
        token, bih, bhh, (half8*)hbuf, bsum, flags);

    k_lstm<<<dim3(NCU), dim3(512), LDS_BYTES, stream>>>(
        wih, whh, bsum, wout, hbuf, ypart, flags, steps);

    k_yout<<<dim3(steps), dim3(64), 0, stream>>>(ypart, bout, out, steps);
}

// Round 7
// 468.765 us; speedup vs baseline: 4.1303x; 1.5090x over previous
//
#include <hip/hip_runtime.h>
#include <cmath>

// Persistent weight-stationary LSTM decode. B=64, H=2048, steps=30.
// gates_t = W_sum @ h_t (t>=1, since x_t == h_t), W_hh @ h_0 at t=0.
// One block per CU (grid=256); weights live in LDS as fp16 MFMA A-frags.
// Grid barrier v4 -- ZERO cache-maintenance: h is published through the
// coherence point with agent-scope relaxed atomic stores (sc1, bypasses the
// non-coherent per-XCD L2); each step writes a FRESH h slot so consumer
// first-touch cached reads cannot hit stale L2 lines (no buffer_inv), and
// published data is already coherent (no buffer_wbl2). Wave 0 issues all h
// stores, drains vmcnt, then releases a per-block flag; consumers spin
// relaxed. R4-R6 showed the barrier cost was the cache-wide wbl2/inv ops
// (~15-50 us/step); this removes them entirely.

#define HID   2048
#define BATCH 64
#define G4    8192
#define NCU   256                 // persistent grid size == CU count
#define HGRP  (HID * BATCH / 8)   // half8 groups per h slot

typedef __attribute__((ext_vector_type(8))) _Float16 half8;
typedef __attribute__((ext_vector_type(4))) float f32x4;

// LDS layout (bytes):
//   [0,      131072)  Wlds   : half8 frags [(mt*64+kt)*64+lane]
//   [131072, 139264)  gates  : f32 [32 rows][64 batch]
//   [139264, 155648)  red    : f32x4 [(srow*4+p)*64+lane]  (4 srows)
//   [155648, 157696)  cbuf   : f32 [8 units][64 batch]
//   [157696, 159744)  ybuf   : f32 [8 units][64 batch]
//   [159744, 160768)  hstage : f16 [64 batch][8 units]
#define LDS_BYTES 160768

// ---- init: pack token -> h slot 0 (B-fragment layout), bsum, barrier flags ----
__global__ void k_init(const float* __restrict__ token, const float* __restrict__ bih,
                       const float* __restrict__ bhh, half8* __restrict__ h0p,
                       float* __restrict__ bsum, unsigned* __restrict__ flags) {
    int g = blockIdx.x * 256 + threadIdx.x;          // [0, 16384)
    int l = g & 63, nt = (g >> 6) & 3, kt = g >> 8;
    int n = nt * 16 + (l & 15);
    int k0 = kt * 32 + (l >> 4) * 8;
    const float4* ps = (const float4*)(token + (size_t)n * HID + k0);
    float4 a = ps[0], b = ps[1];
    half8 v;
    v[0]=(_Float16)a.x; v[1]=(_Float16)a.y; v[2]=(_Float16)a.z; v[3]=(_Float16)a.w;
    v[4]=(_Float16)b.x; v[5]=(_Float16)b.y; v[6]=(_Float16)b.z; v[7]=(_Float16)b.w;
    h0p[g] = v;
    if (g < G4) bsum[g] = bih[g] + bhh[g];
    if (g < NCU) flags[g] = 0u;
}

// ---- the persistent kernel ----
__global__ __launch_bounds__(512, 2)
void k_lstm(const float* __restrict__ wih, const float* __restrict__ whh,
            const float* __restrict__ bsum, const float* __restrict__ wout,
            _Float16* __restrict__ hbuf,     // (steps+1) slots, fragment layout
            float* __restrict__ ypart,       // [steps][NCU][64]
            unsigned* __restrict__ flags, int steps) {
    extern __shared__ char smem[];
    half8*     Wlds   = (half8*)smem;
    float*     gates  = (float*)(smem + 131072);
    f32x4*     red4   = (f32x4*)(smem + 139264);
    float*     cbuf   = (float*)(smem + 155648);
    float*     ybuf   = (float*)(smem + 157696);
    _Float16*  hstage = (_Float16*)(smem + 159744);

    const int tid  = threadIdx.x;
    const int blk  = blockIdx.x;
    const int lane = tid & 63;
    const int w    = tid >> 6;        // wave 0..7
    const int half = w & 1;           // n-tile pair: nt in {2*half, 2*half+1}
    const int ks   = w >> 1;          // k-split slice 0..3 (512 k each)

    // prologue: stage W_hh rows for this block's 32 gate-rows as fp16 A-frags
    for (int idx = tid; idx < 2 * 64 * 64; idx += 512) {
        int l = idx & 63, kt = (idx >> 6) & 63, m2 = idx >> 12;
        int m = l & 15;
        int gate = m2 * 2 + (m >> 3);
        int row  = gate * HID + blk * 8 + (m & 7);
        int col  = kt * 32 + (l >> 4) * 8;
        const float4* p = (const float4*)(whh + (size_t)row * HID + col);
        float4 a = p[0], b = p[1];
        half8 v;
        v[0]=(_Float16)a.x; v[1]=(_Float16)a.y; v[2]=(_Float16)a.z; v[3]=(_Float16)a.w;
        v[4]=(_Float16)b.x; v[5]=(_Float16)b.y; v[6]=(_Float16)b.z; v[7]=(_Float16)b.w;
        Wlds[idx] = v;
    }
    cbuf[tid] = 0.0f;                 // 512 floats, one per thread

    // bias for the gates-writeback waves (ks==0), both m-tiles
    float bias_r[2][4];
    if (ks == 0) {
        const int q = lane >> 4;
        #pragma unroll
        for (int mt2 = 0; mt2 < 2; ++mt2)
            #pragma unroll
            for (int r = 0; r < 4; ++r) {
                int m16 = q * 4 + r;
                bias_r[mt2][r] = bsum[(mt2 * 2 + (m16 >> 3)) * HID + blk * 8 + (m16 & 7)];
            }
    }
    const float wj = wout[blk * 8 + w];   // this wave's output weight (unit j)
    __syncthreads();

    for (int t = 0; t < steps; ++t) {
        const half8* hp = (const half8*)(hbuf + (size_t)t * HID * BATCH);
        // acc[p]: covering (mt, nt=2*half+j)
        f32x4 a00 = {0,0,0,0}, a01 = {0,0,0,0}, a10 = {0,0,0,0}, a11 = {0,0,0,0};
        const int ktb = ks * 16;
        #pragma unroll 8
        for (int kk = 0; kk < 16; ++kk) {
            int kt = ktb + kk;
            half8 av0 = Wlds[(kt) * 64 + lane];            // mt=0
            half8 av1 = Wlds[(64 + kt) * 64 + lane];       // mt=1
            half8 b0  = hp[(kt * 4 + half * 2 + 0) * 64 + lane];
            half8 b1  = hp[(kt * 4 + half * 2 + 1) * 64 + lane];
            a00 = __builtin_amdgcn_mfma_f32_16x16x32_f16(av0, b0, a00, 0, 0, 0);
            a01 = __builtin_amdgcn_mfma_f32_16x16x32_f16(av0, b1, a01, 0, 0, 0);
            a10 = __builtin_amdgcn_mfma_f32_16x16x32_f16(av1, b0, a10, 0, 0, 0);
            a11 = __builtin_amdgcn_mfma_f32_16x16x32_f16(av1, b1, a11, 0, 0, 0);
        }
        // k-split reduction 4 -> 2 -> 1 via LDS
        if (ks == 1 || ks == 3) {
            int srow = (ks == 3 ? 2 : 0) + half;
            red4[(srow * 4 + 0) * 64 + lane] = a00;
            red4[(srow * 4 + 1) * 64 + lane] = a01;
            red4[(srow * 4 + 2) * 64 + lane] = a10;
            red4[(srow * 4 + 3) * 64 + lane] = a11;
        }
        __syncthreads();
        if (ks == 0 || ks == 2) {
            int srow = (ks == 2 ? 2 : 0) + half;
            a00 += red4[(srow * 4 + 0) * 64 + lane];
            a01 += red4[(srow * 4 + 1) * 64 + lane];
            a10 += red4[(srow * 4 + 2) * 64 + lane];
            a11 += red4[(srow * 4 + 3) * 64 + lane];
        }
        __syncthreads();
        if (ks == 2) {
            red4[(half * 4 + 0) * 64 + lane] = a00;
            red4[(half * 4 + 1) * 64 + lane] = a01;
            red4[(half * 4 + 2) * 64 + lane] = a10;
            red4[(half * 4 + 3) * 64 + lane] = a11;
        }
        __syncthreads();
        if (ks == 0) {
            a00 += red4[(half * 4 + 0) * 64 + lane];
            a01 += red4[(half * 4 + 1) * 64 + lane];
            a10 += red4[(half * 4 + 2) * 64 + lane];
            a11 += red4[(half * 4 + 3) * 64 + lane];
            const int q = lane >> 4, col = lane & 15;
            #pragma unroll
            for (int r = 0; r < 4; ++r) {
                float* g0 = gates + (q * 4 + r) * 64 + (half * 2) * 16 + col;       // mt=0
                float* g1 = gates + (16 + q * 4 + r) * 64 + (half * 2) * 16 + col;  // mt=1
                g0[0]  = a00[r] + bias_r[0][r];
                g0[16] = a01[r] + bias_r[0][r];
                g1[0]  = a10[r] + bias_r[1][r];
                g1[16] = a11[r] + bias_r[1][r];
            }
        }
        __syncthreads();
        // pointwise: wave w = local unit j, lane = batch b
        {
            const int b = lane;
            float gi = gates[(0  + w) * 64 + b];
            float gf = gates[(8  + w) * 64 + b];
            float gg = gates[(16 + w) * 64 + b];
            float go = gates[(24 + w) * 64 + b];
            float iv = 1.0f / (1.0f + __expf(-gi));
            float fv = 1.0f / (1.0f + __expf(-gf));
            float gv = tanhf(gg);
            float ov = 1.0f / (1.0f + __expf(-go));
            float cn = fv * cbuf[w * 64 + b] + iv * gv;
            cbuf[w * 64 + b] = cn;
            float hv = ov * tanhf(cn);
            hstage[b * 8 + w] = (_Float16)hv;    // [b][unit], 16 B per batch row
            ybuf[w * 64 + b]  = hv * wj;
        }
        __syncthreads();
        if (tid < 64) {
            // y partial for this block
            float s = ybuf[tid];
            #pragma unroll
            for (int u = 1; u < 8; ++u) s += ybuf[u * 64 + tid];
            ypart[((size_t)t * NCU + blk) * 64 + tid] = s;
            // publish h for batch b=tid: this block's 8 units = 16 contiguous
            // bytes of the B-fragment half8 group. Two 8-byte agent-scope
            // relaxed atomic stores (sc1 -> coherence point, no L2 residency).
            const int b = tid;
            const int kt = blk >> 2, quad = blk & 3;       // fixed per block
            const int nt = b >> 4, lp = quad * 16 + (b & 15);
            const size_t g = (size_t)(kt * 4 + nt) * 64 + lp;
            unsigned long long* dst = (unsigned long long*)
                (hbuf + (size_t)(t + 1) * HID * BATCH + g * 8);
            const unsigned long long* src =
                (const unsigned long long*)(hstage + b * 8);
            unsigned long long v0 = src[0], v1 = src[1];
            __hip_atomic_store(dst,     v0, __ATOMIC_RELAXED, __HIP_MEMORY_SCOPE_AGENT);
            __hip_atomic_store(dst + 1, v1, __ATOMIC_RELAXED, __HIP_MEMORY_SCOPE_AGENT);
        }
        if (t == 0) {
            // upgrade Wlds in place: W_hh -> W_sum (+= W_ih). All step-0 MFMA
            // reads of Wlds are long done (multiple barriers above).
            for (int idx = tid; idx < 2 * 64 * 64; idx += 512) {
                int l = idx & 63, kt = (idx >> 6) & 63, m2 = idx >> 12;
                int m = l & 15;
                int gate = m2 * 2 + (m >> 3);
                int row  = gate * HID + blk * 8 + (m & 7);
                int col  = kt * 32 + (l >> 4) * 8;
                const float4* p = (const float4*)(wih + (size_t)row * HID + col);
                float4 a = p[0], b = p[1];
                half8 v = Wlds[idx];
                v[0] = (_Float16)((float)v[0] + a.x); v[1] = (_Float16)((float)v[1] + a.y);
                v[2] = (_Float16)((float)v[2] + a.z); v[3] = (_Float16)((float)v[3] + a.w);
                v[4] = (_Float16)((float)v[4] + b.x); v[5] = (_Float16)((float)v[5] + b.y);
                v[6] = (_Float16)((float)v[6] + b.z); v[7] = (_Float16)((float)v[7] + b.w);
                Wlds[idx] = v;
            }
        }
        if (t < steps - 1) {
            // grid barrier v4: no cache maintenance (see header).
            // Wave 0 drains its sc1 h stores, then releases this block's flag.
            if (tid < 64) asm volatile("s_waitcnt vmcnt(0)" ::: "memory");
            if (tid == 0)
                __hip_atomic_store(&flags[blk], (unsigned)(t + 1),
                                   __ATOMIC_RELAXED, __HIP_MEMORY_SCOPE_AGENT);
            if (tid < NCU) {
                while (__hip_atomic_load(&flags[tid], __ATOMIC_RELAXED,
                                         __HIP_MEMORY_SCOPE_AGENT) <= (unsigned)t)
                    __builtin_amdgcn_s_sleep(1);
            }
            __syncthreads();           // all flags observed; Wlds upgrade drained
        }
    }
}

// ---- final: out[b][t] = bout + sum over 256 CU partials ----
__global__ void k_yout(const float* __restrict__ ypart, const float* __restrict__ bout,
                       float* __restrict__ out, int steps) {
    int t = blockIdx.x;
    int b = threadIdx.x;                           // 64 threads
    const float* p = ypart + (size_t)t * NCU * 64 + b;
    float s = bout[0];
    #pragma unroll 8
    for (int cu = 0; cu < NCU; ++cu) s += p[(size_t)cu * 64];
    out[(size_t)b * steps + t] = s;
}

extern "C" void kernel_launch(void* const* d_in, const int* in_sizes, int n_in,
                              void* d_out, int out_size, void* d_ws, size_t ws_size,
                              hipStream_t stream) {
    const float* token = (const float*)d_in[0];
    const float* wih   = (const float*)d_in[2];
    const float* whh   = (const float*)d_in[3];
    const float* bih   = (const float*)d_in[4];
    const float* bhh   = (const float*)d_in[5];
    const float* wout  = (const float*)d_in[6];
    const float* bout  = (const float*)d_in[7];
    float* out = (float*)d_out;
    const int steps = out_size / BATCH;            // 30

    char* ws = (char*)d_ws;
    size_t off = 0;
    auto carve = [&](size_t bytes) -> void* {
        void* p = ws + off;
        off = (off + bytes + 255) & ~(size_t)255;
        return p;
    };
    _Float16* hbuf  = (_Float16*)carve((size_t)(steps + 1) * HID * BATCH * 2); // ~8 MB
    float*    bsum  = (float*)carve((size_t)G4 * 4);                   // 32 KB
    float*    ypart = (float*)carve((size_t)steps * NCU * 64 * 4);     // ~2 MB
    unsigned* flags = (unsigned*)carve(NCU * 4);

    hipFuncSetAttribute(reinterpret_cast<const void*>(&k_lstm),
                        hipFuncAttributeMaxDynamicSharedMemorySize, LDS_BYTES);

    k_init<<<dim3(HGRP / 256), dim3(256), 0, stream>>>(
        token, bih, bhh, (half8*)hbuf, bsum, flags);

    k_lstm<<<dim3(NCU), dim3(512), LDS_BYTES, stream>>>(
        wih, whh, bsum, wout, hbuf, ypart, flags, steps);

    k_yout<<<dim3(steps), dim3(64), 0, stream>>>(ypart, bout, out, steps);
}

// Round 8
// 450.741 us; speedup vs baseline: 4.2955x; 1.0400x over previous
//
#include <hip/hip_runtime.h>
#include <cmath>

// Persistent weight-stationary LSTM decode. B=64, H=2048, steps=30.
// gates_t = W_sum @ h_t (t>=1, since x_t == h_t), W_hh @ h_0 at t=0.
// One block per CU (grid=256); weights live in LDS as fp16 MFMA A-frags.
// Sync v5: zero cache-maintenance (R7) + PER-SLICE flag waiting -- wave with
// k-slice ks only needs h units from blocks [ks*64, ks*64+64), so it spins on
// just those 64 flags and starts MFMA as soon as its slice is published
// (overlaps producer skew with compute). Slices are 64KB-aligned: no cache
// line crosses a slice boundary, so first-touch reads stay safe.

#define HID   2048
#define BATCH 64
#define G4    8192
#define NCU   256                 // persistent grid size == CU count
#define HGRP  (HID * BATCH / 8)   // half8 groups per h slot

typedef __attribute__((ext_vector_type(8))) _Float16 half8;
typedef __attribute__((ext_vector_type(4))) float f32x4;

// LDS layout (bytes):
//   [0,      131072)  Wlds   : half8 frags [(mt*64+kt)*64+lane]
//   [131072, 139264)  gates  : f32 [32 rows][64 batch]
//   [139264, 155648)  red    : f32x4 [(srow*4+p)*64+lane]  (4 srows)
//   [155648, 157696)  cbuf   : f32 [8 units][64 batch]
//   [157696, 159744)  ybuf   : f32 [8 units][64 batch]
//   [159744, 160768)  hstage : f16 [64 batch][8 units]
#define LDS_BYTES 160768

// ---- init: pack token -> h slot 0 (B-fragment layout), bsum, barrier flags ----
__global__ void k_init(const float* __restrict__ token, const float* __restrict__ bih,
                       const float* __restrict__ bhh, half8* __restrict__ h0p,
                       float* __restrict__ bsum, unsigned* __restrict__ flags) {
    int g = blockIdx.x * 256 + threadIdx.x;          // [0, 16384)
    int l = g & 63, nt = (g >> 6) & 3, kt = g >> 8;
    int n = nt * 16 + (l & 15);
    int k0 = kt * 32 + (l >> 4) * 8;
    const float4* ps = (const float4*)(token + (size_t)n * HID + k0);
    float4 a = ps[0], b = ps[1];
    half8 v;
    v[0]=(_Float16)a.x; v[1]=(_Float16)a.y; v[2]=(_Float16)a.z; v[3]=(_Float16)a.w;
    v[4]=(_Float16)b.x; v[5]=(_Float16)b.y; v[6]=(_Float16)b.z; v[7]=(_Float16)b.w;
    h0p[g] = v;
    if (g < G4) bsum[g] = bih[g] + bhh[g];
    if (g < NCU) flags[g] = 0u;
}

// ---- the persistent kernel ----
__global__ __launch_bounds__(512, 2)
void k_lstm(const float* __restrict__ wih, const float* __restrict__ whh,
            const float* __restrict__ bsum, const float* __restrict__ wout,
            _Float16* __restrict__ hbuf,     // (steps+1) slots, fragment layout
            float* __restrict__ ypart,       // [steps][NCU][64]
            unsigned* __restrict__ flags, int steps) {
    extern __shared__ char smem[];
    half8*     Wlds   = (half8*)smem;
    float*     gates  = (float*)(smem + 131072);
    f32x4*     red4   = (f32x4*)(smem + 139264);
    float*     cbuf   = (float*)(smem + 155648);
    float*     ybuf   = (float*)(smem + 157696);
    _Float16*  hstage = (_Float16*)(smem + 159744);

    const int tid  = threadIdx.x;
    const int blk  = blockIdx.x;
    const int lane = tid & 63;
    const int w    = tid >> 6;        // wave 0..7
    const int half = w & 1;           // n-tile pair: nt in {2*half, 2*half+1}
    const int ks   = w >> 1;          // k-split slice 0..3 (512 k each)

    // prologue: stage W_hh rows for this block's 32 gate-rows as fp16 A-frags
    for (int idx = tid; idx < 2 * 64 * 64; idx += 512) {
        int l = idx & 63, kt = (idx >> 6) & 63, m2 = idx >> 12;
        int m = l & 15;
        int gate = m2 * 2 + (m >> 3);
        int row  = gate * HID + blk * 8 + (m & 7);
        int col  = kt * 32 + (l >> 4) * 8;
        const float4* p = (const float4*)(whh + (size_t)row * HID + col);
        float4 a = p[0], b = p[1];
        half8 v;
        v[0]=(_Float16)a.x; v[1]=(_Float16)a.y; v[2]=(_Float16)a.z; v[3]=(_Float16)a.w;
        v[4]=(_Float16)b.x; v[5]=(_Float16)b.y; v[6]=(_Float16)b.z; v[7]=(_Float16)b.w;
        Wlds[idx] = v;
    }
    cbuf[tid] = 0.0f;                 // 512 floats, one per thread

    // bias for the gates-writeback waves (ks==0), both m-tiles
    float bias_r[2][4];
    if (ks == 0) {
        const int q = lane >> 4;
        #pragma unroll
        for (int mt2 = 0; mt2 < 2; ++mt2)
            #pragma unroll
            for (int r = 0; r < 4; ++r) {
                int m16 = q * 4 + r;
                bias_r[mt2][r] = bsum[(mt2 * 2 + (m16 >> 3)) * HID + blk * 8 + (m16 & 7)];
            }
    }
    const float wj = wout[blk * 8 + w];   // this wave's output weight (unit j)
    __syncthreads();

    for (int t = 0; t < steps; ++t) {
        const half8* hp = (const half8*)(hbuf + (size_t)t * HID * BATCH);
        // acc: covering (mt, nt=2*half+j)
        f32x4 a00 = {0,0,0,0}, a01 = {0,0,0,0}, a10 = {0,0,0,0}, a11 = {0,0,0,0};
        const int ktb = ks * 16;
        #pragma unroll
        for (int kk = 0; kk < 16; ++kk) {
            int kt = ktb + kk;
            half8 av0 = Wlds[(kt) * 64 + lane];            // mt=0
            half8 av1 = Wlds[(64 + kt) * 64 + lane];       // mt=1
            half8 b0  = hp[(kt * 4 + half * 2 + 0) * 64 + lane];
            half8 b1  = hp[(kt * 4 + half * 2 + 1) * 64 + lane];
            a00 = __builtin_amdgcn_mfma_f32_16x16x32_f16(av0, b0, a00, 0, 0, 0);
            a01 = __builtin_amdgcn_mfma_f32_16x16x32_f16(av0, b1, a01, 0, 0, 0);
            a10 = __builtin_amdgcn_mfma_f32_16x16x32_f16(av1, b0, a10, 0, 0, 0);
            a11 = __builtin_amdgcn_mfma_f32_16x16x32_f16(av1, b1, a11, 0, 0, 0);
        }
        // k-split reduction 4 -> 2 -> 1 via LDS
        if (ks == 1 || ks == 3) {
            int srow = (ks == 3 ? 2 : 0) + half;
            red4[(srow * 4 + 0) * 64 + lane] = a00;
            red4[(srow * 4 + 1) * 64 + lane] = a01;
            red4[(srow * 4 + 2) * 64 + lane] = a10;
            red4[(srow * 4 + 3) * 64 + lane] = a11;
        }
        __syncthreads();
        if (ks == 0 || ks == 2) {
            int srow = (ks == 2 ? 2 : 0) + half;
            a00 += red4[(srow * 4 + 0) * 64 + lane];
            a01 += red4[(srow * 4 + 1) * 64 + lane];
            a10 += red4[(srow * 4 + 2) * 64 + lane];
            a11 += red4[(srow * 4 + 3) * 64 + lane];
        }
        __syncthreads();
        if (ks == 2) {
            red4[(half * 4 + 0) * 64 + lane] = a00;
            red4[(half * 4 + 1) * 64 + lane] = a01;
            red4[(half * 4 + 2) * 64 + lane] = a10;
            red4[(half * 4 + 3) * 64 + lane] = a11;
        }
        __syncthreads();
        if (ks == 0) {
            a00 += red4[(half * 4 + 0) * 64 + lane];
            a01 += red4[(half * 4 + 1) * 64 + lane];
            a10 += red4[(half * 4 + 2) * 64 + lane];
            a11 += red4[(half * 4 + 3) * 64 + lane];
            const int q = lane >> 4, col = lane & 15;
            #pragma unroll
            for (int r = 0; r < 4; ++r) {
                float* g0 = gates + (q * 4 + r) * 64 + (half * 2) * 16 + col;       // mt=0
                float* g1 = gates + (16 + q * 4 + r) * 64 + (half * 2) * 16 + col;  // mt=1
                g0[0]  = a00[r] + bias_r[0][r];
                g0[16] = a01[r] + bias_r[0][r];
                g1[0]  = a10[r] + bias_r[1][r];
                g1[16] = a11[r] + bias_r[1][r];
            }
        }
        __syncthreads();
        // pointwise: wave w = local unit j, lane = batch b
        {
            const int b = lane;
            float gi = gates[(0  + w) * 64 + b];
            float gf = gates[(8  + w) * 64 + b];
            float gg = gates[(16 + w) * 64 + b];
            float go = gates[(24 + w) * 64 + b];
            float iv = 1.0f / (1.0f + __expf(-gi));
            float fv = 1.0f / (1.0f + __expf(-gf));
            float gv = tanhf(gg);
            float ov = 1.0f / (1.0f + __expf(-go));
            float cn = fv * cbuf[w * 64 + b] + iv * gv;
            cbuf[w * 64 + b] = cn;
            float hv = ov * tanhf(cn);
            hstage[b * 8 + w] = (_Float16)hv;    // [b][unit], 16 B per batch row
            ybuf[w * 64 + b]  = hv * wj;
        }
        __syncthreads();
        if (w == 0) {
            // publish h for batch b=lane: this block's 8 units = 16 contiguous
            // bytes of the B-fragment half8 group. Two 8-byte agent-scope
            // relaxed atomic stores (sc1 -> coherence point, no L2 residency).
            const int b = lane;
            const int kt = blk >> 2, quad = blk & 3;       // fixed per block
            const int nt = b >> 4, lp = quad * 16 + (b & 15);
            const size_t g = (size_t)(kt * 4 + nt) * 64 + lp;
            unsigned long long* dst = (unsigned long long*)
                (hbuf + (size_t)(t + 1) * HID * BATCH + g * 8);
            const unsigned long long* src =
                (const unsigned long long*)(hstage + b * 8);
            unsigned long long v0 = src[0], v1 = src[1];
            __hip_atomic_store(dst,     v0, __ATOMIC_RELAXED, __HIP_MEMORY_SCOPE_AGENT);
            __hip_atomic_store(dst + 1, v1, __ATOMIC_RELAXED, __HIP_MEMORY_SCOPE_AGENT);
            asm volatile("s_waitcnt vmcnt(0)" ::: "memory");  // h at coherence point
            if (lane == 0 && t < steps - 1)
                __hip_atomic_store(&flags[blk], (unsigned)(t + 1),
                                   __ATOMIC_RELAXED, __HIP_MEMORY_SCOPE_AGENT);
            // y partial (after flag release: off the critical path)
            float s = ybuf[lane];
            #pragma unroll
            for (int u = 1; u < 8; ++u) s += ybuf[u * 64 + lane];
            ypart[((size_t)t * NCU + blk) * 64 + lane] = s;
        }
        if (t == 0) {
            // upgrade Wlds in place: W_hh -> W_sum (+= W_ih); must complete in
            // ALL waves before any wave's step-1 MFMA -> block barrier after.
            for (int idx = tid; idx < 2 * 64 * 64; idx += 512) {
                int l = idx & 63, kt = (idx >> 6) & 63, m2 = idx >> 12;
                int m = l & 15;
                int gate = m2 * 2 + (m >> 3);
                int row  = gate * HID + blk * 8 + (m & 7);
                int col  = kt * 32 + (l >> 4) * 8;
                const float4* p = (const float4*)(wih + (size_t)row * HID + col);
                float4 a = p[0], b = p[1];
                half8 v = Wlds[idx];
                v[0] = (_Float16)((float)v[0] + a.x); v[1] = (_Float16)((float)v[1] + a.y);
                v[2] = (_Float16)((float)v[2] + a.z); v[3] = (_Float16)((float)v[3] + a.w);
                v[4] = (_Float16)((float)v[4] + b.x); v[5] = (_Float16)((float)v[5] + b.y);
                v[6] = (_Float16)((float)v[6] + b.z); v[7] = (_Float16)((float)v[7] + b.w);
                Wlds[idx] = v;
            }
            __syncthreads();
        }
        if (t < steps - 1) {
            // per-slice wait: this wave consumes only k units [ks*512,(ks+1)*512)
            // = producer blocks [ks*64, ks*64+64). Lane li waits flags[ks*64+li].
            while (__hip_atomic_load(&flags[ks * 64 + lane], __ATOMIC_RELAXED,
                                     __HIP_MEMORY_SCOPE_AGENT) <= (unsigned)t)
                __builtin_amdgcn_s_sleep(1);
            asm volatile("" ::: "memory");   // no h loads hoisted above the spin
        }
    }
}

// ---- final: out[b][t] = bout + sum over 256 CU partials ----
__global__ __launch_bounds__(512)
void k_yout(const float* __restrict__ ypart, const float* __restrict__ bout,
            float* __restrict__ out, int steps) {
    __shared__ float red[8][64];
    int t = blockIdx.x;
    int tid = threadIdx.x;
    int b = tid & 63, ch = tid >> 6;               // 8 chunks x 32 CUs
    const float* p = ypart + (size_t)t * NCU * 64 + b;
    float s = 0.0f;
    #pragma unroll 8
    for (int cu = ch * 32; cu < ch * 32 + 32; ++cu) s += p[(size_t)cu * 64];
    red[ch][b] = s;
    __syncthreads();
    if (tid < 64) {
        float r = bout[0];
        #pragma unroll
        for (int u = 0; u < 8; ++u) r += red[u][tid];
        out[(size_t)tid * steps + t] = r;
    }
}

extern "C" void kernel_launch(void* const* d_in, const int* in_sizes, int n_in,
                              void* d_out, int out_size, void* d_ws, size_t ws_size,
                              hipStream_t stream) {
    const float* token = (const float*)d_in[0];
    const float* wih   = (const float*)d_in[2];
    const float* whh   = (const float*)d_in[3];
    const float* bih   = (const float*)d_in[4];
    const float* bhh   = (const float*)d_in[5];
    const float* wout  = (const float*)d_in[6];
    const float* bout  = (const float*)d_in[7];
    float* out = (float*)d_out;
    const int steps = out_size / BATCH;            // 30

    char* ws = (char*)d_ws;
    size_t off = 0;
    auto carve = [&](size_t bytes) -> void* {
        void* p = ws + off;
        off = (off + bytes + 255) & ~(size_t)255;
        return p;
    };
    _Float16* hbuf  = (_Float16*)carve((size_t)(steps + 1) * HID * BATCH * 2); // ~8 MB
    float*    bsum  = (float*)carve((size_t)G4 * 4);                   // 32 KB
    float*    ypart = (float*)carve((size_t)steps * NCU * 64 * 4);     // ~2 MB
    unsigned* flags = (unsigned*)carve(NCU * 4);

    hipFuncSetAttribute(reinterpret_cast<const void*>(&k_lstm),
                        hipFuncAttributeMaxDynamicSharedMemorySize, LDS_BYTES);

    k_init<<<dim3(HGRP / 256), dim3(256), 0, stream>>>(
        token, bih, bhh, (half8*)hbuf, bsum, flags);

    k_lstm<<<dim3(NCU), dim3(512), LDS_BYTES, stream>>>(
        wih, whh, bsum, wout, hbuf, ypart, flags, steps);

    k_yout<<<dim3(steps), dim3(512), 0, stream>>>(ypart, bout, out, steps);
}